// Round 1
// baseline (79.573 us; speedup 1.0000x reference)
//
#include <hip/hip_runtime.h>
#include <hip/hip_bf16.h>

// Problem constants: B=4, LQ=LK=1024, NHEADS=16, DK=64, D_MODEL=1024.
// out[b,i,d] = 0.125 * sum_{n,k} q[b,i,n,k] * T[b,n,k,d] + fc_b[d]
// T[b,n,k,d] = sum_j k[b,j,n,k] * fc_w[d, j*16+n]

typedef unsigned short u16;
typedef __bf16 bf16x8 __attribute__((ext_vector_type(8)));
typedef float f32x4 __attribute__((ext_vector_type(4)));

__device__ __forceinline__ u16 f2bf(float f) {
  union { float f; unsigned u; } in;
  in.f = f;
  unsigned u = in.u;
  u += 0x7fffu + ((u >> 16) & 1u);  // RNE
  return (u16)(u >> 16);
}

// ---------------- prep: q f32 -> bf16 (identity layout) ----------------
__global__ __launch_bounds__(256) void conv_q(const float* __restrict__ in,
                                              u16* __restrict__ out) {
  int idx = blockIdx.x * 256 + threadIdx.x;  // 262144 threads
#pragma unroll
  for (int it = 0; it < 4; ++it) {
    int i = it * 262144 + idx;
    float4 v = reinterpret_cast<const float4*>(in)[i];
    ushort4 o;
    o.x = f2bf(v.x); o.y = f2bf(v.y); o.z = f2bf(v.z); o.w = f2bf(v.w);
    reinterpret_cast<ushort4*>(out)[i] = o;
  }
}

// ---------------- prep: Kt[n][b*64+k][j] = k[b][j][n][kk] ----------------
__global__ __launch_bounds__(256) void trans_k(const float* __restrict__ k,
                                               u16* __restrict__ Kt) {
  const int jt = blockIdx.x;  // 16 tiles of 64 j
  const int n  = blockIdx.y;  // 16
  const int b  = blockIdx.z;  // 4
  const int tid = threadIdx.x;
  __shared__ u16 lds[64][65];  // [kk][jj]
  const int j0 = jt * 64;
#pragma unroll
  for (int it = 0; it < 4; ++it) {
    int idx = it * 256 + tid;
    int jj = idx >> 4;       // 0..63
    int c4 = idx & 15;       // 16 float4 per row of 64 k
    float4 v = *reinterpret_cast<const float4*>(
        &k[(((size_t)b * 1024 + j0 + jj) * 16 + n) * 64 + c4 * 4]);
    lds[c4 * 4 + 0][jj] = f2bf(v.x);
    lds[c4 * 4 + 1][jj] = f2bf(v.y);
    lds[c4 * 4 + 2][jj] = f2bf(v.z);
    lds[c4 * 4 + 3][jj] = f2bf(v.w);
  }
  __syncthreads();
#pragma unroll
  for (int it = 0; it < 4; ++it) {
    int idx = it * 256 + tid;
    int kk = idx >> 4;
    int c4 = idx & 15;
    ushort4 o;
    o.x = lds[kk][c4 * 4 + 0]; o.y = lds[kk][c4 * 4 + 1];
    o.z = lds[kk][c4 * 4 + 2]; o.w = lds[kk][c4 * 4 + 3];
    *reinterpret_cast<ushort4*>(
        &Kt[((size_t)n * 256 + b * 64 + kk) * 1024 + j0 + c4 * 4]) = o;
  }
}

// ---------------- prep: Wt[n][d][j] = fc_w[d][j*16+n] ----------------
__global__ __launch_bounds__(256) void deint_w(const float* __restrict__ w,
                                               u16* __restrict__ Wt) {
  const int jt = blockIdx.x;  // 16 tiles of 1024 jn cols (64 j)
  const int dt = blockIdx.y;  // 64 tiles of 16 d rows
  const int tid = threadIdx.x;
  __shared__ u16 lds[16][16][66];  // [n][dd][j]
#pragma unroll
  for (int it = 0; it < 16; ++it) {
    int idx = it * 256 + tid;  // 0..4095 float4
    int dd = idx >> 8;         // 0..15
    int c4 = idx & 255;        // float4 within 1024-col slab
    float4 v = *reinterpret_cast<const float4*>(
        &w[(size_t)(dt * 16 + dd) * 16384 + jt * 1024 + c4 * 4]);
    int n0 = (c4 * 4) & 15;    // {0,4,8,12}
    int jl = c4 >> 2;          // 0..63
    lds[n0 + 0][dd][jl] = f2bf(v.x);
    lds[n0 + 1][dd][jl] = f2bf(v.y);
    lds[n0 + 2][dd][jl] = f2bf(v.z);
    lds[n0 + 3][dd][jl] = f2bf(v.w);
  }
  __syncthreads();
#pragma unroll
  for (int it = 0; it < 16; ++it) {
    int idx = it * 256 + tid;
    int row = idx >> 4;        // 0..255 = (n,dd)
    int n = row >> 4, dd = row & 15;
    int c4 = idx & 15;
    ushort4 o;
    o.x = lds[n][dd][c4 * 4 + 0]; o.y = lds[n][dd][c4 * 4 + 1];
    o.z = lds[n][dd][c4 * 4 + 2]; o.w = lds[n][dd][c4 * 4 + 3];
    *reinterpret_cast<ushort4*>(
        &Wt[(size_t)n * 1048576 + (size_t)(dt * 16 + dd) * 1024 + jt * 64 + c4 * 4]) = o;
  }
}

// ---------------- GEMM: C = A @ B^T (A: MxK row-major, B: NxK row-major) ----------------
// STAGE 1: per-n batch: A=Wt[n] (1024d x 1024j), B=Kt[n] (256bk x 1024j),
//          C -> T2t[b][d][n*64+k] bf16.
// STAGE 2: per-b batch: A=Qb[b] (1024i x 1024nk), B=T2t[b] (1024d x 1024nk),
//          C -> out[b][i][d] f32, * 0.125 + bias[d].
template <int STAGE>
__global__ __launch_bounds__(256) void gemm_bt(const u16* __restrict__ Abase,
                                               const u16* __restrict__ Bbase,
                                               u16* __restrict__ CoutBf,
                                               float* __restrict__ CoutF,
                                               const float* __restrict__ bias) {
  const int tid = threadIdx.x;
  const int wid = tid >> 6;
  const int lane = tid & 63;
  const int batch = blockIdx.y;

  const int tn_tiles = (STAGE == 1) ? 2 : 8;
  const int tm = blockIdx.x / tn_tiles;
  const int tn = blockIdx.x % tn_tiles;

  const u16* A = Abase + (size_t)batch * 1048576;
  const u16* B = Bbase + (size_t)batch * ((STAGE == 1) ? 262144 : 1048576);

  __shared__ u16 Atile[128 * 32];
  __shared__ u16 Btile[128 * 32];

  const int row0A = tm * 128;
  const int row0B = tn * 128;
  const int wr = wid >> 1;
  const int wc = wid & 1;
  const int laneRow = lane & 15;
  const int laneK = (lane >> 4) * 8;

  f32x4 acc[4][4] = {};

  for (int kt = 0; kt < 1024; kt += 32) {
    // stage 128x32 bf16 tiles of A and B via async global->LDS (16B/lane)
#pragma unroll
    for (int j = 0; j < 2; ++j) {
      int chunk = j * 4 + wid;               // 8 chunks of 1KB
      int r = chunk * 16 + (lane >> 2);      // row within tile
      int c = (lane & 3) * 8;                // col element
      const u16* gA = A + (size_t)(row0A + r) * 1024 + kt + c;
      const u16* gB = B + (size_t)(row0B + r) * 1024 + kt + c;
      u16* lA = Atile + chunk * 512;         // wave-uniform LDS base
      u16* lB = Btile + chunk * 512;
      __builtin_amdgcn_global_load_lds((const __attribute__((address_space(1))) void*)gA,
                                       (__attribute__((address_space(3))) void*)lA, 16, 0, 0);
      __builtin_amdgcn_global_load_lds((const __attribute__((address_space(1))) void*)gB,
                                       (__attribute__((address_space(3))) void*)lB, 16, 0, 0);
    }
    __syncthreads();

    bf16x8 af[4], bq[4];
#pragma unroll
    for (int mi = 0; mi < 4; ++mi)
      af[mi] = *reinterpret_cast<const bf16x8*>(
          &Atile[(wr * 64 + mi * 16 + laneRow) * 32 + laneK]);
#pragma unroll
    for (int ni = 0; ni < 4; ++ni)
      bq[ni] = *reinterpret_cast<const bf16x8*>(
          &Btile[(wc * 64 + ni * 16 + laneRow) * 32 + laneK]);

#pragma unroll
    for (int mi = 0; mi < 4; ++mi)
#pragma unroll
      for (int ni = 0; ni < 4; ++ni)
        acc[mi][ni] = __builtin_amdgcn_mfma_f32_16x16x32_bf16(af[mi], bq[ni], acc[mi][ni], 0, 0, 0);

    __syncthreads();
  }

  // epilogue: D frag layout col=lane&15, row=(lane>>4)*4+q
#pragma unroll
  for (int mi = 0; mi < 4; ++mi) {
#pragma unroll
    for (int ni = 0; ni < 4; ++ni) {
      int colg = tn * 128 + wc * 64 + ni * 16 + laneRow;
#pragma unroll
      for (int q = 0; q < 4; ++q) {
        int rowg = tm * 128 + wr * 64 + mi * 16 + (lane >> 4) * 4 + q;
        if (STAGE == 1) {
          // C row = d, col = b*64+k  ->  T2t[b][d][n*64+k]
          size_t off = (size_t)(colg >> 6) * 1048576 + (size_t)rowg * 1024 +
                       (size_t)batch * 64 + (colg & 63);
          CoutBf[off] = f2bf(acc[mi][ni][q]);
        } else {
          CoutF[(size_t)batch * 1048576 + (size_t)rowg * 1024 + colg] =
              acc[mi][ni][q] * 0.125f + bias[colg];
        }
      }
    }
  }
}

extern "C" void kernel_launch(void* const* d_in, const int* in_sizes, int n_in,
                              void* d_out, int out_size, void* d_ws, size_t ws_size,
                              hipStream_t stream) {
  const float* q    = (const float*)d_in[0];
  const float* k    = (const float*)d_in[1];
  // d_in[2] = v — unused by the reference output
  const float* fc_w = (const float*)d_in[3];
  const float* fc_b = (const float*)d_in[4];
  float* out = (float*)d_out;

  char* ws = (char*)d_ws;
  if (ws_size < 58720256) return;  // need 56 MB scratch
  u16* Qb  = (u16*)(ws);             // [4][1024][1024]   8.4 MB
  u16* Kt  = (u16*)(ws + 8388608);   // [16][256][1024]   8.4 MB
  u16* Wt  = (u16*)(ws + 16777216);  // [16][1024][1024] 33.6 MB
  u16* T2t = (u16*)(ws + 50331648);  // [4][1024][1024]   8.4 MB

  conv_q<<<1024, 256, 0, stream>>>(q, Qb);
  trans_k<<<dim3(16, 16, 4), 256, 0, stream>>>(k, Kt);
  deint_w<<<dim3(16, 64), 256, 0, stream>>>(fc_w, Wt);
  gemm_bt<1><<<dim3(16, 16), 256, 0, stream>>>(Wt, Kt, T2t, nullptr, nullptr);
  gemm_bt<2><<<dim3(64, 4), 256, 0, stream>>>(Qb, T2t, nullptr, out, fc_b);
}

// Round 2
// 61.590 us; speedup vs baseline: 1.2920x; 1.2920x over previous
//
#include <hip/hip_runtime.h>
#include <hip/hip_bf16.h>

// Problem: B=4, LQ=LK=1024, NHEADS=16, DK=64, D_MODEL=1024.
// out[b,i,d] = 0.125 * sum_{n,k} q[b,i,n,k] * T[b,n,k,d] + fc_b[d]
// T[b,n,k,d] = sum_j k[b,j,n,k] * fc_w[d, j*16+n]
// Factored: stage1 T2t[b][d][n*64+k] = Wt[n] @ Kt[n]^T (16 batches, 1024x256x1024)
//           stage2 out[b] = 0.125 * Qb[b] @ T2t[b]^T + bias (4 batches, 1024^3)

typedef unsigned short u16;
typedef __bf16 bf16x8 __attribute__((ext_vector_type(8)));
typedef float f32x4 __attribute__((ext_vector_type(4)));

__device__ __forceinline__ u16 f2bf(float f) {
  union { float f; unsigned u; } in;
  in.f = f;
  unsigned u = in.u;
  u += 0x7fffu + ((u >> 16) & 1u);  // RNE
  return (u16)(u >> 16);
}

// ---------------- fused prep: q->bf16, k transpose, fc_w de-interleave ----------------
__global__ __launch_bounds__(256) void prep(const float* __restrict__ q,
                                            const float* __restrict__ k,
                                            const float* __restrict__ w,
                                            u16* __restrict__ Qb,
                                            u16* __restrict__ Kt,
                                            u16* __restrict__ Wt) {
  __shared__ u16 lds[16 * 16 * 66];  // 33 KB, reused per role
  const int tid = threadIdx.x;
  const int bid = blockIdx.x;

  if (bid < 1024) {
    // role A: Qb = bf16(q), identity layout
    int idx = bid * 256 + tid;
#pragma unroll
    for (int it = 0; it < 4; ++it) {
      int i = it * 262144 + idx;
      float4 v = reinterpret_cast<const float4*>(q)[i];
      ushort4 o;
      o.x = f2bf(v.x); o.y = f2bf(v.y); o.z = f2bf(v.z); o.w = f2bf(v.w);
      reinterpret_cast<ushort4*>(Qb)[i] = o;
    }
  } else if (bid < 2048) {
    // role B: Kt[n][b*64+kk][j] = k[b][j][n][kk]
    int e = bid - 1024;
    int jt = e & 15, n = (e >> 4) & 15, b = e >> 8;
    auto l2 = reinterpret_cast<u16(*)[65]>(lds);  // [kk][jj]
    const int j0 = jt * 64;
#pragma unroll
    for (int it = 0; it < 4; ++it) {
      int idx = it * 256 + tid;
      int jj = idx >> 4;
      int c4 = idx & 15;
      float4 v = *reinterpret_cast<const float4*>(
          &k[(((size_t)b * 1024 + j0 + jj) * 16 + n) * 64 + c4 * 4]);
      l2[c4 * 4 + 0][jj] = f2bf(v.x);
      l2[c4 * 4 + 1][jj] = f2bf(v.y);
      l2[c4 * 4 + 2][jj] = f2bf(v.z);
      l2[c4 * 4 + 3][jj] = f2bf(v.w);
    }
    __syncthreads();
#pragma unroll
    for (int it = 0; it < 4; ++it) {
      int idx = it * 256 + tid;
      int kk = idx >> 4;
      int c4 = idx & 15;
      ushort4 o;
      o.x = l2[kk][c4 * 4 + 0]; o.y = l2[kk][c4 * 4 + 1];
      o.z = l2[kk][c4 * 4 + 2]; o.w = l2[kk][c4 * 4 + 3];
      *reinterpret_cast<ushort4*>(
          &Kt[((size_t)n * 256 + b * 64 + kk) * 1024 + j0 + c4 * 4]) = o;
    }
  } else {
    // role C: Wt[n][d][j] = fc_w[d][j*16+n]
    int e = bid - 2048;
    int jt = e & 15, dt = e >> 4;
    auto l3 = reinterpret_cast<u16(*)[16][66]>(lds);  // [n][dd][j]
#pragma unroll
    for (int it = 0; it < 16; ++it) {
      int idx = it * 256 + tid;
      int dd = idx >> 8;
      int c4 = idx & 255;
      float4 v = *reinterpret_cast<const float4*>(
          &w[(size_t)(dt * 16 + dd) * 16384 + jt * 1024 + c4 * 4]);
      int n0 = (c4 * 4) & 15;
      int jl = c4 >> 2;
      l3[n0 + 0][dd][jl] = f2bf(v.x);
      l3[n0 + 1][dd][jl] = f2bf(v.y);
      l3[n0 + 2][dd][jl] = f2bf(v.z);
      l3[n0 + 3][dd][jl] = f2bf(v.w);
    }
    __syncthreads();
#pragma unroll
    for (int it = 0; it < 16; ++it) {
      int idx = it * 256 + tid;
      int row = idx >> 4;
      int n = row >> 4, dd = row & 15;
      int c4 = idx & 15;
      ushort4 o;
      o.x = l3[n][dd][c4 * 4 + 0]; o.y = l3[n][dd][c4 * 4 + 1];
      o.z = l3[n][dd][c4 * 4 + 2]; o.w = l3[n][dd][c4 * 4 + 3];
      *reinterpret_cast<ushort4*>(
          &Wt[(size_t)n * 1048576 + (size_t)(dt * 16 + dd) * 1024 + jt * 64 + c4 * 4]) = o;
    }
  }
}

// ---------------- pipelined GEMM: C = A @ B^T, K=1024, tile 128x128, BK=64 ----------------
// 4 LDS buffers (128 KB), depth-3 prefetch, 1 barrier per K-step, counted vmcnt.
// XOR-swizzled LDS (both sides: pre-swizzled gload_lds source + swizzled ds_read).
template <int VM>
__device__ __forceinline__ void waitVm() {
  if constexpr (VM == 16) asm volatile("s_waitcnt vmcnt(16)" ::: "memory");
  else if constexpr (VM == 8) asm volatile("s_waitcnt vmcnt(8)" ::: "memory");
  else asm volatile("s_waitcnt vmcnt(0)" ::: "memory");
}

template <int TN_TILES, int STAGE>
__global__ __launch_bounds__(256, 1) void gemm_bt(const u16* __restrict__ Abase,
                                                  const u16* __restrict__ Bbase,
                                                  u16* __restrict__ CoutBf,
                                                  float* __restrict__ CoutF,
                                                  const float* __restrict__ bias) {
  __shared__ u16 AB[4][2][128 * 64];  // [buf][A/B][row*64+col], 128 KB
  const int tid = threadIdx.x;
  const int wid = tid >> 6;
  const int lane = tid & 63;
  const int batch = blockIdx.y;
  const int tm = blockIdx.x / TN_TILES;
  const int tn = blockIdx.x % TN_TILES;

  const u16* A = Abase + (size_t)batch * 1048576;
  const u16* B = Bbase + (size_t)batch * ((STAGE == 1) ? 262144 : 1048576);
  const int row0A = tm * 128, row0B = tn * 128;

  const int wr = wid >> 1;
  const int wc = wid & 1;
  const int laneRow = lane & 15;
  const int hi8 = (lane >> 4) * 8;
  const int swz = (lane & 7) * 8;

  f32x4 acc[4][4] = {};

  // stage one 128x64 A-tile + B-tile pair into buffer (tIdx&3).
  // LDS dest is linear (wave-uniform base + lane*16); source col is
  // pre-swizzled: colblk_src = colblk_dst ^ (row&7)  [16B blocks].
  auto stage = [&](int tIdx) {
    const int kt = tIdx * 64;
    u16* lA = &AB[tIdx & 3][0][0];
    u16* lB = &AB[tIdx & 3][1][0];
#pragma unroll
    for (int i = 0; i < 4; ++i) {
      int p = i * 256 + tid;                  // 16B chunk id, 0..1023
      int r = p >> 3;                         // row 0..127
      int sc = ((p & 7) ^ (r & 7)) * 8;       // swizzled source col (elems)
      const u16* gA = A + (size_t)(row0A + r) * 1024 + kt + sc;
      const u16* gB = B + (size_t)(row0B + r) * 1024 + kt + sc;
      __builtin_amdgcn_global_load_lds(
          (const __attribute__((address_space(1))) void*)gA,
          (__attribute__((address_space(3))) void*)(lA + i * 2048 + wid * 512), 16, 0, 0);
      __builtin_amdgcn_global_load_lds(
          (const __attribute__((address_space(1))) void*)gB,
          (__attribute__((address_space(3))) void*)(lB + i * 2048 + wid * 512), 16, 0, 0);
    }
  };

  auto compute = [&](int tIdx) {
    const u16* At = &AB[tIdx & 3][0][0];
    const u16* Bt = &AB[tIdx & 3][1][0];
    bf16x8 af[2][4], bq[2][4];
#pragma unroll
    for (int kh = 0; kh < 2; ++kh) {
      int cs = (kh * 32 + hi8) ^ swz;  // swizzled read col
#pragma unroll
      for (int mi = 0; mi < 4; ++mi)
        af[kh][mi] = *reinterpret_cast<const bf16x8*>(
            &At[(wr * 64 + mi * 16 + laneRow) * 64 + cs]);
#pragma unroll
      for (int ni = 0; ni < 4; ++ni)
        bq[kh][ni] = *reinterpret_cast<const bf16x8*>(
            &Bt[(wc * 64 + ni * 16 + laneRow) * 64 + cs]);
    }
#pragma unroll
    for (int kh = 0; kh < 2; ++kh)
#pragma unroll
      for (int mi = 0; mi < 4; ++mi)
#pragma unroll
        for (int ni = 0; ni < 4; ++ni)
          acc[mi][ni] = __builtin_amdgcn_mfma_f32_16x16x32_bf16(
              af[kh][mi], bq[kh][ni], acc[mi][ni], 0, 0, 0);
  };

  // prologue: 3 tiles in flight (24 loads/thread outstanding)
  stage(0); stage(1); stage(2);

  // main: wait tile t (vmcnt(16) = 2 newer tiles outstanding), barrier, prefetch t+3
  for (int t = 0; t < 13; ++t) {
    waitVm<16>();
    __builtin_amdgcn_s_barrier();
    stage(t + 3);
    compute(t);
  }
  waitVm<16>(); __builtin_amdgcn_s_barrier(); compute(13);
  waitVm<8>();  __builtin_amdgcn_s_barrier(); compute(14);
  waitVm<0>();  __builtin_amdgcn_s_barrier(); compute(15);

  // epilogue: D frag layout col=lane&15, row=(lane>>4)*4+q
#pragma unroll
  for (int mi = 0; mi < 4; ++mi) {
#pragma unroll
    for (int ni = 0; ni < 4; ++ni) {
      int colg = tn * 128 + wc * 64 + ni * 16 + laneRow;
#pragma unroll
      for (int qq = 0; qq < 4; ++qq) {
        int rowg = tm * 128 + wr * 64 + mi * 16 + (lane >> 4) * 4 + qq;
        if (STAGE == 1) {
          size_t off = (size_t)(colg >> 6) * 1048576 + (size_t)rowg * 1024 +
                       (size_t)batch * 64 + (colg & 63);
          CoutBf[off] = f2bf(acc[mi][ni][qq]);
        } else {
          CoutF[(size_t)batch * 1048576 + (size_t)rowg * 1024 + colg] =
              acc[mi][ni][qq] * 0.125f + bias[colg];
        }
      }
    }
  }
}

extern "C" void kernel_launch(void* const* d_in, const int* in_sizes, int n_in,
                              void* d_out, int out_size, void* d_ws, size_t ws_size,
                              hipStream_t stream) {
  const float* q    = (const float*)d_in[0];
  const float* k    = (const float*)d_in[1];
  // d_in[2] = v — unused by the reference output
  const float* fc_w = (const float*)d_in[3];
  const float* fc_b = (const float*)d_in[4];
  float* out = (float*)d_out;

  char* ws = (char*)d_ws;
  if (ws_size < 58720256) return;  // need 56 MB scratch
  u16* Qb  = (u16*)(ws);             // [4][1024][1024]   8.4 MB
  u16* Kt  = (u16*)(ws + 8388608);   // [16][256][1024]   8.4 MB
  u16* Wt  = (u16*)(ws + 16777216);  // [16][1024][1024] 33.6 MB
  u16* T2t = (u16*)(ws + 50331648);  // [4][1024][1024]   8.4 MB

  prep<<<3072, 256, 0, stream>>>(q, k, fc_w, Qb, Kt, Wt);
  gemm_bt<2, 1><<<dim3(16, 16), 256, 0, stream>>>(Wt, Kt, T2t, nullptr, nullptr);
  gemm_bt<8, 2><<<dim3(64, 4), 256, 0, stream>>>(Qb, T2t, nullptr, out, fc_b);
}

// Round 3
// 61.439 us; speedup vs baseline: 1.2952x; 1.0025x over previous
//
#include <hip/hip_runtime.h>
#include <hip/hip_bf16.h>

// Problem: B=4, LQ=LK=1024, NHEADS=16, DK=64, D_MODEL=1024.
// out[b,i,d] = 0.125 * sum_{n,k} q[b,i,n,k] * T[b,n,k,d] + fc_b[d]
// T[b,n,k,d] = sum_j k[b,j,n,k] * fc_w[d, j*16+n]
// Factored: stage1 T2t[b][d][n*64+k] = Wt[n] @ Kt[n]^T (16 batches, 1024x256x1024)
//           stage2 out[b] = 0.125 * Qb[b] @ T2t[b]^T + bias (4 batches, 1024^3)

typedef unsigned short u16;
typedef unsigned int u32;
typedef __bf16 bf16x8 __attribute__((ext_vector_type(8)));
typedef float f32x4 __attribute__((ext_vector_type(4)));

__device__ __forceinline__ u16 f2bf(float f) {
  union { float f; unsigned u; } in;
  in.f = f;
  unsigned u = in.u;
  u += 0x7fffu + ((u >> 16) & 1u);  // RNE
  return (u16)(u >> 16);
}

// ---------------- fused prep: q->bf16, k transpose, fc_w de-interleave ----------------
// grid: [0,1024) role A (q conv), [1024,2048) role B (k transpose),
//       [2048,6144) role C (fc_w de-interleave, 4 d-rows per block).
__global__ __launch_bounds__(256) void prep(const float* __restrict__ q,
                                            const float* __restrict__ k,
                                            const float* __restrict__ w,
                                            u16* __restrict__ Qb,
                                            u16* __restrict__ Kt,
                                            u16* __restrict__ Wt) {
  __shared__ u16 lds[4672];  // 9.3 KB, reused per role
  const int tid = threadIdx.x;
  const int bid = blockIdx.x;

  if (bid < 1024) {
    // role A: Qb = bf16(q), identity layout. 16KB read / 8KB write per block.
    int idx = bid * 256 + tid;
#pragma unroll
    for (int it = 0; it < 4; ++it) {
      int i = it * 262144 + idx;
      float4 v = reinterpret_cast<const float4*>(q)[i];
      ushort4 o;
      o.x = f2bf(v.x); o.y = f2bf(v.y); o.z = f2bf(v.z); o.w = f2bf(v.w);
      reinterpret_cast<ushort4*>(Qb)[i] = o;
    }
  } else if (bid < 2048) {
    // role B: Kt[n][b*64+kk][j] = k[b][j][n][kk]. 16KB read / 8KB write.
    int e = bid - 1024;
    int jt = e & 15, n = (e >> 4) & 15, b = e >> 8;
    auto l2 = reinterpret_cast<u16(*)[65]>(lds);  // [kk][jj] (fits: 8320B)
    const int j0 = jt * 64;
#pragma unroll
    for (int it = 0; it < 4; ++it) {
      int idx = it * 256 + tid;
      int jj = idx >> 4;
      int c4 = idx & 15;
      float4 v = *reinterpret_cast<const float4*>(
          &k[(((size_t)b * 1024 + j0 + jj) * 16 + n) * 64 + c4 * 4]);
      l2[c4 * 4 + 0][jj] = f2bf(v.x);
      l2[c4 * 4 + 1][jj] = f2bf(v.y);
      l2[c4 * 4 + 2][jj] = f2bf(v.z);
      l2[c4 * 4 + 3][jj] = f2bf(v.w);
    }
    __syncthreads();
#pragma unroll
    for (int it = 0; it < 4; ++it) {
      int idx = it * 256 + tid;
      int kk = idx >> 4;
      int c4 = idx & 15;
      ushort4 o;
      o.x = l2[kk][c4 * 4 + 0]; o.y = l2[kk][c4 * 4 + 1];
      o.z = l2[kk][c4 * 4 + 2]; o.w = l2[kk][c4 * 4 + 3];
      *reinterpret_cast<ushort4*>(
          &Kt[((size_t)n * 256 + b * 64 + kk) * 1024 + j0 + c4 * 4]) = o;
    }
  } else {
    // role C: Wt[n][d][j] = fc_w[d][j*16+n]. 4 d-rows per block.
    // LDS layout: u16 addr = dd*1154 + jl*18 + n  (dd<4, jl<64, n<16).
    //  - dd-stride 1154 (577 words, odd -> spreads banks across dd)
    //  - j-pad 18 -> conflict-free-ish both sides (<=2-way)
    // Write side: 2x packed b32 (bf16 pairs). Read side: 4x scalar u16.
    int e = bid - 2048;
    int jt = e & 15;            // 64-j slab
    int d0 = (e >> 4) * 4;      // 4 d rows
    u32* lds32 = reinterpret_cast<u32*>(lds);
#pragma unroll
    for (int it = 0; it < 4; ++it) {
      int idx = it * 256 + tid;
      int dd = idx >> 8;         // 0..3
      int c4 = idx & 255;        // float4 within 1024-jn slab
      float4 v = *reinterpret_cast<const float4*>(
          &w[(size_t)(d0 + dd) * 16384 + jt * 1024 + c4 * 4]);
      int n0 = (c4 & 3) * 4;     // {0,4,8,12}
      int jl = c4 >> 2;          // 0..63
      u32 lo = (u32)f2bf(v.x) | ((u32)f2bf(v.y) << 16);
      u32 hi = (u32)f2bf(v.z) | ((u32)f2bf(v.w) << 16);
      int a0 = dd * 1154 + jl * 18 + n0;  // even
      lds32[a0 >> 1] = lo;
      lds32[(a0 >> 1) + 1] = hi;
    }
    __syncthreads();
#pragma unroll
    for (int it = 0; it < 4; ++it) {
      int idx = it * 256 + tid;
      int row = idx >> 4;        // 0..63 = (dd,n)
      int n = row & 15, dd = row >> 4;
      int c4 = idx & 15;
      int base = dd * 1154 + n;
      ushort4 o;
      o.x = lds[base + (c4 * 4 + 0) * 18];
      o.y = lds[base + (c4 * 4 + 1) * 18];
      o.z = lds[base + (c4 * 4 + 2) * 18];
      o.w = lds[base + (c4 * 4 + 3) * 18];
      *reinterpret_cast<ushort4*>(
          &Wt[(size_t)n * 1048576 + (size_t)(d0 + dd) * 1024 + jt * 64 + c4 * 4]) = o;
    }
  }
}

// ---------------- pipelined GEMM: C = A @ B^T, K=1024, tile 128x128, BK=64 ----------------
// 4 LDS buffers (128 KB), depth-3 prefetch, 1 barrier per K-step, counted vmcnt.
// XOR-swizzled LDS (both sides: pre-swizzled gload_lds source + swizzled ds_read).
template <int VM>
__device__ __forceinline__ void waitVm() {
  if constexpr (VM == 16) asm volatile("s_waitcnt vmcnt(16)" ::: "memory");
  else if constexpr (VM == 8) asm volatile("s_waitcnt vmcnt(8)" ::: "memory");
  else asm volatile("s_waitcnt vmcnt(0)" ::: "memory");
}

template <int TN_TILES, int STAGE>
__global__ __launch_bounds__(256, 1) void gemm_bt(const u16* __restrict__ Abase,
                                                  const u16* __restrict__ Bbase,
                                                  u16* __restrict__ CoutBf,
                                                  float* __restrict__ CoutF,
                                                  const float* __restrict__ bias) {
  __shared__ u16 AB[4][2][128 * 64];  // [buf][A/B][row*64+col], 128 KB
  const int tid = threadIdx.x;
  const int wid = tid >> 6;
  const int lane = tid & 63;
  const int batch = blockIdx.y;
  const int tm = blockIdx.x / TN_TILES;
  const int tn = blockIdx.x % TN_TILES;

  const u16* A = Abase + (size_t)batch * 1048576;
  const u16* B = Bbase + (size_t)batch * ((STAGE == 1) ? 262144 : 1048576);
  const int row0A = tm * 128, row0B = tn * 128;

  const int wr = wid >> 1;
  const int wc = wid & 1;
  const int laneRow = lane & 15;
  const int hi8 = (lane >> 4) * 8;
  const int swz = (lane & 7) * 8;

  f32x4 acc[4][4] = {};

  // stage one 128x64 A-tile + B-tile pair into buffer (tIdx&3).
  // LDS dest is linear (wave-uniform base + lane*16); source col is
  // pre-swizzled: colblk_src = colblk_dst ^ (row&7)  [16B blocks].
  auto stage = [&](int tIdx) {
    const int kt = tIdx * 64;
    u16* lA = &AB[tIdx & 3][0][0];
    u16* lB = &AB[tIdx & 3][1][0];
#pragma unroll
    for (int i = 0; i < 4; ++i) {
      int p = i * 256 + tid;                  // 16B chunk id, 0..1023
      int r = p >> 3;                         // row 0..127
      int sc = ((p & 7) ^ (r & 7)) * 8;       // swizzled source col (elems)
      const u16* gA = A + (size_t)(row0A + r) * 1024 + kt + sc;
      const u16* gB = B + (size_t)(row0B + r) * 1024 + kt + sc;
      __builtin_amdgcn_global_load_lds(
          (const __attribute__((address_space(1))) void*)gA,
          (__attribute__((address_space(3))) void*)(lA + i * 2048 + wid * 512), 16, 0, 0);
      __builtin_amdgcn_global_load_lds(
          (const __attribute__((address_space(1))) void*)gB,
          (__attribute__((address_space(3))) void*)(lB + i * 2048 + wid * 512), 16, 0, 0);
    }
  };

  auto compute = [&](int tIdx) {
    const u16* At = &AB[tIdx & 3][0][0];
    const u16* Bt = &AB[tIdx & 3][1][0];
    bf16x8 af[2][4], bq[2][4];
#pragma unroll
    for (int kh = 0; kh < 2; ++kh) {
      int cs = (kh * 32 + hi8) ^ swz;  // swizzled read col
#pragma unroll
      for (int mi = 0; mi < 4; ++mi)
        af[kh][mi] = *reinterpret_cast<const bf16x8*>(
            &At[(wr * 64 + mi * 16 + laneRow) * 64 + cs]);
#pragma unroll
      for (int ni = 0; ni < 4; ++ni)
        bq[kh][ni] = *reinterpret_cast<const bf16x8*>(
            &Bt[(wc * 64 + ni * 16 + laneRow) * 64 + cs]);
    }
#pragma unroll
    for (int kh = 0; kh < 2; ++kh)
#pragma unroll
      for (int mi = 0; mi < 4; ++mi)
#pragma unroll
        for (int ni = 0; ni < 4; ++ni)
          acc[mi][ni] = __builtin_amdgcn_mfma_f32_16x16x32_bf16(
              af[kh][mi], bq[kh][ni], acc[mi][ni], 0, 0, 0);
  };

  // prologue: 3 tiles in flight (24 loads/thread outstanding)
  stage(0); stage(1); stage(2);

  // main: wait tile t (vmcnt(16) = 2 newer tiles outstanding), barrier, prefetch t+3
  for (int t = 0; t < 13; ++t) {
    waitVm<16>();
    __builtin_amdgcn_s_barrier();
    stage(t + 3);
    compute(t);
  }
  waitVm<16>(); __builtin_amdgcn_s_barrier(); compute(13);
  waitVm<8>();  __builtin_amdgcn_s_barrier(); compute(14);
  waitVm<0>();  __builtin_amdgcn_s_barrier(); compute(15);

  // epilogue: D frag layout col=lane&15, row=(lane>>4)*4+q
#pragma unroll
  for (int mi = 0; mi < 4; ++mi) {
#pragma unroll
    for (int ni = 0; ni < 4; ++ni) {
      int colg = tn * 128 + wc * 64 + ni * 16 + laneRow;
#pragma unroll
      for (int qq = 0; qq < 4; ++qq) {
        int rowg = tm * 128 + wr * 64 + mi * 16 + (lane >> 4) * 4 + qq;
        if (STAGE == 1) {
          size_t off = (size_t)(colg >> 6) * 1048576 + (size_t)rowg * 1024 +
                       (size_t)batch * 64 + (colg & 63);
          CoutBf[off] = f2bf(acc[mi][ni][qq]);
        } else {
          CoutF[(size_t)batch * 1048576 + (size_t)rowg * 1024 + colg] =
              acc[mi][ni][qq] * 0.125f + bias[colg];
        }
      }
    }
  }
}

extern "C" void kernel_launch(void* const* d_in, const int* in_sizes, int n_in,
                              void* d_out, int out_size, void* d_ws, size_t ws_size,
                              hipStream_t stream) {
  const float* q    = (const float*)d_in[0];
  const float* k    = (const float*)d_in[1];
  // d_in[2] = v — unused by the reference output
  const float* fc_w = (const float*)d_in[3];
  const float* fc_b = (const float*)d_in[4];
  float* out = (float*)d_out;

  char* ws = (char*)d_ws;
  if (ws_size < 58720256) return;  // need 56 MB scratch
  u16* Qb  = (u16*)(ws);             // [4][1024][1024]   8.4 MB
  u16* Kt  = (u16*)(ws + 8388608);   // [16][256][1024]   8.4 MB
  u16* Wt  = (u16*)(ws + 16777216);  // [16][1024][1024] 33.6 MB
  u16* T2t = (u16*)(ws + 50331648);  // [4][1024][1024]   8.4 MB

  prep<<<6144, 256, 0, stream>>>(q, k, fc_w, Qb, Kt, Wt);
  gemm_bt<2, 1><<<dim3(16, 16), 256, 0, stream>>>(Wt, Kt, T2t, nullptr, nullptr);
  gemm_bt<8, 2><<<dim3(64, 4), 256, 0, stream>>>(Qb, T2t, nullptr, out, fc_b);
}